// Round 8
// baseline (2435.331 us; speedup 1.0000x reference)
//
#include <hip/hip_runtime.h>

#define B_ 256
#define T_ 256
#define H_ 300
#define IN_ 16
#define NT_ 75          // gate tiles (1200/16)
#define KSR_ 10         // recurrent K slabs (300 -> 320)
#define HP_ 320         // padded h row stride (elements)
#define MEMB_ 10        // member blocks per group
#define WPB_ 8          // waves per block (512 threads)

typedef __attribute__((ext_vector_type(8))) short short8;
typedef __attribute__((ext_vector_type(4))) float f32x4;
typedef unsigned int uint32;

union S8U { short8 s; uint32 u[4]; };

__device__ __forceinline__ unsigned short f2bf(float f) {
    uint32 u = __float_as_uint(f);
    u = u + 0x7fffu + ((u >> 16) & 1u);   // RNE
    return (unsigned short)(u >> 16);
}
__device__ __forceinline__ float bf2f(unsigned short h) {
    return __uint_as_float(((uint32)h) << 16);
}
__device__ __forceinline__ float sigm(float x) {
    float e = __expf(-x);
    return __builtin_amdgcn_rcpf(1.f + e);
}
__device__ __forceinline__ float tanh_f(float x) {
    float xc = fminf(fmaxf(x, -15.f), 15.f);
    float e = __expf(2.f * xc);
    return (e - 1.f) * __builtin_amdgcn_rcpf(e + 1.f);
}

// --- asm loads: force the load instruction; VGPR residency is enforced by
// __launch_bounds__(512, 2) (min 2 waves/EU -> 256-VGPR cap, no spill).
// offset: is 13-bit SIGNED: keep immediates <= 3072, extra bases past 4 KB.
template<int OFF>
__device__ __forceinline__ void gl16(short8& r, const void* p) {
    static_assert(OFF >= 0 && OFF <= 4095, "13-bit signed offset");
    asm volatile("global_load_dwordx4 %0, %1, off offset:%2"
                 : "=v"(r) : "v"(p), "i"(OFF));
}
// IF$ (coherence-point) ops: sc0 sc1, bypass L1/L2, no cache-maintenance
template<int OFF>
__device__ __forceinline__ void gl16c(short8& r, const void* p) {
    static_assert(OFF >= 0 && OFF <= 4095, "13-bit signed offset");
    asm volatile("global_load_dwordx4 %0, %1, off offset:%2 sc0 sc1"
                 : "=v"(r) : "v"(p), "i"(OFF));
}
__device__ __forceinline__ void vm0() {
    asm volatile("s_waitcnt vmcnt(0)" ::: "memory");
}
__device__ __forceinline__ void st2c(unsigned short* p, unsigned short v) {
    uint32 vv = v;
    asm volatile("global_store_short %0, %1, off sc0 sc1" :: "v"(p), "v"(vv) : "memory");
}
__device__ __forceinline__ void st4c(int* p, int v) {
    asm volatile("global_store_dword %0, %1, off sc0 sc1" :: "v"(p), "v"(v) : "memory");
}

// load 10 slabs (1024 B apart) from base p via 3 bases, immediates <= 3072
#define LOAD10(PFX, v0,v1,v2,v3,v4,v5,v6,v7,v8,v9, p)                    \
    do {                                                                 \
        const char* _b0 = (const char*)(p);                              \
        const char* _b1 = _b0 + 4096;                                    \
        const char* _b2 = _b0 + 8192;                                    \
        PFX<0>(v0, _b0);    PFX<1024>(v1, _b0);                          \
        PFX<2048>(v2, _b0); PFX<3072>(v3, _b0);                          \
        PFX<0>(v4, _b1);    PFX<1024>(v5, _b1);                          \
        PFX<2048>(v6, _b1); PFX<3072>(v7, _b1);                          \
        PFX<0>(v8, _b2);    PFX<1024>(v9, _b2);                          \
    } while (0)

#define MF(w_, a_, acc_) acc_ = __builtin_amdgcn_mfma_f32_16x16x32_bf16(w_, a_, acc_, 0, 0, 0)

// ---------------------------------------------------------------------------
// Weight packing into bf16 MFMA A-fragments, gate rows permuted unit-major.
// ---------------------------------------------------------------------------
__device__ __forceinline__ void pack_one(int idx, const float* __restrict__ W,
                                         int K, int KS, uint32* __restrict__ dst)
{
    int lane = idx & 63, ts = idx >> 6;
    int slab = ts % KS, tile = ts / KS;
    int rp = tile * 16 + (lane & 15);
    int jj = rp >> 2, g = rp & 3;
    int r = g * H_ + jj;
    int kb = slab * 32 + (lane >> 4) * 8;
    #pragma unroll
    for (int p = 0; p < 4; ++p) {
        int k0 = kb + 2 * p, k1 = k0 + 1;
        float v0 = (k0 < K) ? W[(size_t)r * K + k0] : 0.f;
        float v1 = (k1 < K) ? W[(size_t)r * K + k1] : 0.f;
        dst[(size_t)idx * 4 + p] = (uint32)f2bf(v0) | ((uint32)f2bf(v1) << 16);
    }
}

__global__ void pack_kernel(const float* __restrict__ Wih0, const float* __restrict__ Whh0,
                            const float* __restrict__ bih0, const float* __restrict__ bhh0,
                            const float* __restrict__ Wih1, const float* __restrict__ Whh1,
                            const float* __restrict__ bih1, const float* __restrict__ bhh1,
                            uint32* __restrict__ wr0, uint32* __restrict__ wg0,
                            uint32* __restrict__ wr1, uint32* __restrict__ wg1,
                            float* __restrict__ b0p, float* __restrict__ b1p)
{
    const int C0 = NT_ * KSR_ * 64;   // 48000
    const int C1 = NT_ * 64;          // 4800
    int id = blockIdx.x * 256 + threadIdx.x;
    if (id < C0) pack_one(id, Whh0, H_, KSR_, wr0);
    else if (id < C0 + C1) pack_one(id - C0, Wih0, IN_, 1, wg0);
    else if (id < 2 * C0 + C1) pack_one(id - C0 - C1, Whh1, H_, KSR_, wr1);
    else if (id < 3 * C0 + C1) pack_one(id - 2 * C0 - C1, Wih1, H_, KSR_, wg1);
    else if (id < 3 * C0 + C1 + 1200) {
        int p = id - 3 * C0 - C1;
        int jj = p >> 2, g = p & 3, r = g * H_ + jj;
        b0p[p] = bih0[r] + bhh0[r];
    } else if (id < 3 * C0 + C1 + 2400) {
        int p = id - 3 * C0 - C1 - 1200;
        int jj = p >> 2, g = p & 3, r = g * H_ + jj;
        b1p[p] = bih1[r] + bhh1[r];
    }
}

// ---------------------------------------------------------------------------
// Layer 0, single dispatch over all 256 steps. 160 blocks x 512 threads.
// blockIdx = member*16 + g; wave owns tile member*8+wave (80 waves/group).
// Whh0 (10 slabs) + Wih0 (1 slab) pinned (VGPR cap 256 via launch_bounds).
// Exchange: per-wave epoch flags + 2-slot fragment buffer, all at IF$.
// ---------------------------------------------------------------------------
__global__ __launch_bounds__(512, 2) void lstm_rec0(
    const float* __restrict__ x, const short8* __restrict__ wr,
    const short8* __restrict__ wxp, const float* __restrict__ bp,
    unsigned short* __restrict__ hrm, unsigned short* __restrict__ hx,
    int* __restrict__ flags)
{
    const int tid = threadIdx.x;
    const int wave = tid >> 6, lane = tid & 63;
    const int g = blockIdx.x & 15, member = blockIdx.x >> 4;
    const int rawwt = member * WPB_ + wave;          // 0..79
    const bool act = rawwt < NT_;
    const int wtile = act ? rawwt : NT_ - 1;
    const int m = lane & 15, oct = lane >> 4;

    // pinned weights
    const short8* wq = wr + (size_t)wtile * (KSR_ * 64) + lane;
    short8 w0, w1, w2, w3, w4, w5, w6, w7, w8, w9, wxv;
    LOAD10(gl16, w0, w1, w2, w3, w4, w5, w6, w7, w8, w9, wq);
    gl16<0>(wxv, wxp + (size_t)wtile * 64 + lane);
    const f32x4 b4 = *(const f32x4*)&bp[wtile * 16 + oct * 4];
    vm0();
    __builtin_amdgcn_sched_barrier(0);

    unsigned short* hxg = hx + (size_t)g * 10240;    // 2 slots x 5120 shorts
    int* fbase = flags + g * 128;
    const int* fp1 = fbase + lane;
    const int* fp2 = fbase + 64 + (lane & 15);
    int* fw = fbase + rawwt;

    const int jj = wtile * 4 + oct;
    const int fragaddr = (((jj >> 5) * 64 + ((jj >> 3) & 3) * 16 + m) << 3) + (jj & 7);
    unsigned short* hxs0 = hxg + fragaddr;
    unsigned short* hxs1 = hxg + 5120 + fragaddr;
    unsigned short* hout = hrm + ((size_t)(g * 16 + m) * T_) * HP_ + jj;
    const float* xrow = x + ((size_t)(g * 16 + m) * T_) * IN_ + (oct & 1) * 8;
    const unsigned short* exb = hxg + lane * 8;

    const short8 z8 = {0, 0, 0, 0, 0, 0, 0, 0};
    short8 a0 = z8, a1 = z8, a2 = z8, a3 = z8, a4 = z8,
           a5 = z8, a6 = z8, a7 = z8, a8 = z8, a9 = z8;
    float c = 0.f;

    #pragma unroll 1
    for (int t = 0; t < T_; ++t) {
        // x slab (plain loads, off critical path)
        const float* xr = xrow + (size_t)t * IN_;
        f32x4 xf0 = *(const f32x4*)xr;
        f32x4 xf1 = *(const f32x4*)(xr + 4);
        S8U xu;
        xu.u[0] = (uint32)f2bf(xf0[0]) | ((uint32)f2bf(xf0[1]) << 16);
        xu.u[1] = (uint32)f2bf(xf0[2]) | ((uint32)f2bf(xf0[3]) << 16);
        xu.u[2] = (uint32)f2bf(xf1[0]) | ((uint32)f2bf(xf1[1]) << 16);
        xu.u[3] = (uint32)f2bf(xf1[2]) | ((uint32)f2bf(xf1[3]) << 16);
        short8 xa = (oct < 2) ? xu.s : z8;

        // pre-poll chain: x contribution
        f32x4 accX = {0.f, 0.f, 0.f, 0.f};
        MF(wxv, xa, accX);

        if (t > 0) {
            // wait for all 80 waves of the group to have published h[t-1]
            int it = 0;
            for (;;) {
                int f1, f2;
                asm volatile("global_load_dword %0, %2, off sc0 sc1\n\t"
                             "global_load_dword %1, %3, off sc0 sc1\n\t"
                             "s_waitcnt vmcnt(0)"
                             : "=&v"(f1), "=&v"(f2) : "v"(fp1), "v"(fp2) : "memory");
                unsigned long long bad = __ballot(f1 < t) | (__ballot(f2 < t) & 0xffffull);
                if (bad == 0) break;
                __builtin_amdgcn_s_sleep(1);
                if (++it > (1 << 22)) break;   // bailout: wrong > hung
            }
            const unsigned short* sb = exb + (size_t)(((t - 1) & 1) * 5120);
            LOAD10(gl16c, a0, a1, a2, a3, a4, a5, a6, a7, a8, a9, sb);
            vm0();
            __builtin_amdgcn_sched_barrier(0);
        }

        f32x4 accA = {0.f, 0.f, 0.f, 0.f}, accB = {0.f, 0.f, 0.f, 0.f};
        MF(w0, a0, accA); MF(w1, a1, accB);
        MF(w2, a2, accA); MF(w3, a3, accB);
        MF(w4, a4, accA); MF(w5, a5, accB);
        MF(w6, a6, accA); MF(w7, a7, accB);
        MF(w8, a8, accA); MF(w9, a9, accB);

        float gi = sigm(accA[0] + accB[0] + accX[0] + b4[0]);
        float gf = sigm(accA[1] + accB[1] + accX[1] + b4[1]);
        float gg = tanh_f(accA[2] + accB[2] + accX[2] + b4[2]);
        float go = sigm(accA[3] + accB[3] + accX[3] + b4[3]);
        float cn = gf * c + gi * gg;
        c = cn;
        unsigned short hb = f2bf(go * tanh_f(cn));
        if (act) {
            st2c((t & 1) ? hxs1 : hxs0, hb);       // exchange (IF$)
            hout[(size_t)t * HP_] = hb;            // row-major for layer 1 (L2)
        }
        vm0();                                     // stores visible at IF$
        if (lane == 0) st4c(fw, t + 1);            // publish epoch
    }
}

// ---------------------------------------------------------------------------
// Layer 1, single dispatch. Same geometry; Whh1 AND Wih1 pinned (80 VGPRs).
// Per step: b-frags (h0, plain/L2, pre-poll) -> acc1 chain overlaps the
// flag wait -> exchange a-frags -> acc0 chain -> epilogue.
// ---------------------------------------------------------------------------
__global__ __launch_bounds__(512, 2) void lstm_rec1(
    const unsigned short* __restrict__ h0rm, const short8* __restrict__ wr,
    const short8* __restrict__ wxq, const float* __restrict__ bp,
    unsigned short* __restrict__ hrm, unsigned short* __restrict__ hx,
    int* __restrict__ flags)
{
    const int tid = threadIdx.x;
    const int wave = tid >> 6, lane = tid & 63;
    const int g = blockIdx.x & 15, member = blockIdx.x >> 4;
    const int rawwt = member * WPB_ + wave;
    const bool act = rawwt < NT_;
    const int wtile = act ? rawwt : NT_ - 1;
    const int m = lane & 15, oct = lane >> 4;

    const short8* wq = wr + (size_t)wtile * (KSR_ * 64) + lane;
    const short8* xq = wxq + (size_t)wtile * (KSR_ * 64) + lane;
    short8 w0, w1, w2, w3, w4, w5, w6, w7, w8, w9;
    short8 x0, x1, x2, x3, x4, x5, x6, x7, x8, x9;
    LOAD10(gl16, w0, w1, w2, w3, w4, w5, w6, w7, w8, w9, wq);
    LOAD10(gl16, x0, x1, x2, x3, x4, x5, x6, x7, x8, x9, xq);
    const f32x4 b4 = *(const f32x4*)&bp[wtile * 16 + oct * 4];
    vm0();
    __builtin_amdgcn_sched_barrier(0);

    unsigned short* hxg = hx + (size_t)g * 10240;
    int* fbase = flags + g * 128;
    const int* fp1 = fbase + lane;
    const int* fp2 = fbase + 64 + (lane & 15);
    int* fw = fbase + rawwt;

    const int jj = wtile * 4 + oct;
    const int fragaddr = (((jj >> 5) * 64 + ((jj >> 3) & 3) * 16 + m) << 3) + (jj & 7);
    unsigned short* hxs0 = hxg + fragaddr;
    unsigned short* hxs1 = hxg + 5120 + fragaddr;
    unsigned short* hout = hrm + ((size_t)(g * 16 + m) * T_) * HP_ + jj;
    const unsigned short* h0b = h0rm + ((size_t)(g * 16 + m) * T_) * HP_ + oct * 8;
    const unsigned short* exb = hxg + lane * 8;

    const short8 z8 = {0, 0, 0, 0, 0, 0, 0, 0};
    short8 a0 = z8, a1 = z8, a2 = z8, a3 = z8, a4 = z8,
           a5 = z8, a6 = z8, a7 = z8, a8 = z8, a9 = z8;
    float c = 0.f;

    #pragma unroll 1
    for (int t = 0; t < T_; ++t) {
        // h0 fragments for this step (plain, L2-served; ready since kernel start)
        const unsigned short* br = h0b + (size_t)t * HP_;
        short8 b0 = *(const short8*)(br);
        short8 b1 = *(const short8*)(br + 32);
        short8 b2 = *(const short8*)(br + 64);
        short8 b3 = *(const short8*)(br + 96);
        short8 b4f = *(const short8*)(br + 128);
        short8 b5 = *(const short8*)(br + 160);
        short8 b6 = *(const short8*)(br + 192);
        short8 b7 = *(const short8*)(br + 224);
        short8 b8 = *(const short8*)(br + 256);
        short8 b9 = *(const short8*)(br + 288);

        // pre-poll chain: Wih1 @ h0 (independent of the recurrence)
        f32x4 acc1 = {0.f, 0.f, 0.f, 0.f};
        MF(x0, b0, acc1); MF(x1, b1, acc1); MF(x2, b2, acc1);
        MF(x3, b3, acc1); MF(x4, b4f, acc1); MF(x5, b5, acc1);
        MF(x6, b6, acc1); MF(x7, b7, acc1); MF(x8, b8, acc1);
        MF(x9, b9, acc1);

        if (t > 0) {
            int it = 0;
            for (;;) {
                int f1, f2;
                asm volatile("global_load_dword %0, %2, off sc0 sc1\n\t"
                             "global_load_dword %1, %3, off sc0 sc1\n\t"
                             "s_waitcnt vmcnt(0)"
                             : "=&v"(f1), "=&v"(f2) : "v"(fp1), "v"(fp2) : "memory");
                unsigned long long bad = __ballot(f1 < t) | (__ballot(f2 < t) & 0xffffull);
                if (bad == 0) break;
                __builtin_amdgcn_s_sleep(1);
                if (++it > (1 << 22)) break;
            }
            const unsigned short* sb = exb + (size_t)(((t - 1) & 1) * 5120);
            LOAD10(gl16c, a0, a1, a2, a3, a4, a5, a6, a7, a8, a9, sb);
            vm0();
            __builtin_amdgcn_sched_barrier(0);
        }

        f32x4 accA = {0.f, 0.f, 0.f, 0.f}, accB = {0.f, 0.f, 0.f, 0.f};
        MF(w0, a0, accA); MF(w1, a1, accB);
        MF(w2, a2, accA); MF(w3, a3, accB);
        MF(w4, a4, accA); MF(w5, a5, accB);
        MF(w6, a6, accA); MF(w7, a7, accB);
        MF(w8, a8, accA); MF(w9, a9, accB);

        float gi = sigm(accA[0] + accB[0] + acc1[0] + b4[0]);
        float gf = sigm(accA[1] + accB[1] + acc1[1] + b4[1]);
        float gg = tanh_f(accA[2] + accB[2] + acc1[2] + b4[2]);
        float go = sigm(accA[3] + accB[3] + acc1[3] + b4[3]);
        float cn = gf * c + gi * gg;
        c = cn;
        unsigned short hb = f2bf(go * tanh_f(cn));
        if (act) {
            st2c((t & 1) ? hxs1 : hxs0, hb);
            hout[(size_t)t * HP_] = hb;            // row-major for head
        }
        vm0();
        if (lane == 0) st4c(fw, t + 1);
    }
}

// ---------------------------------------------------------------------------
// MLP head: W1/W2/W3 staged in LDS (broadcast reads), one thread per position.
// ---------------------------------------------------------------------------
__global__ __launch_bounds__(256) void head_kernel(
    const unsigned short* __restrict__ h1,
    const float* __restrict__ W1, const float* __restrict__ b1,
    const float* __restrict__ W2, const float* __restrict__ b2,
    const float* __restrict__ W3, const float* __restrict__ b3,
    float* __restrict__ out)
{
    __shared__ float w1s[9000];     // 30x300
    __shared__ float w2s[3200];     // 100x32 (padded)
    __shared__ float w3s[100];
    __shared__ float b1s[30];
    __shared__ float b2s[100];
    const int tid = threadIdx.x;
    for (int i = tid; i < 9000; i += 256) w1s[i] = W1[i];
    for (int i = tid; i < 3000; i += 256) w2s[(i / 30) * 32 + (i % 30)] = W2[i];
    if (tid < 100) { w3s[tid] = W3[tid]; b2s[tid] = b2[tid]; }
    if (tid < 30)  b1s[tid] = b1[tid];
    __syncthreads();

    const int pos = blockIdx.x * 256 + tid;
    const unsigned short* hr = h1 + (size_t)pos * HP_;
    float t1[30];
    #pragma unroll
    for (int j = 0; j < 30; ++j) t1[j] = b1s[j];
    for (int kc = 0; kc < H_; kc += 4) {
        uint32 u0 = *(const uint32*)(hr + kc);
        uint32 u1 = *(const uint32*)(hr + kc + 2);
        float h0v = bf2f((unsigned short)(u0 & 0xffffu));
        float h1v = bf2f((unsigned short)(u0 >> 16));
        float h2v = bf2f((unsigned short)(u1 & 0xffffu));
        float h3v = bf2f((unsigned short)(u1 >> 16));
        #pragma unroll
        for (int j = 0; j < 30; ++j) {
            const f32x4 wv = *(const f32x4*)&w1s[j * H_ + kc];
            t1[j] += h0v * wv[0] + h1v * wv[1] + h2v * wv[2] + h3v * wv[3];
        }
    }
    #pragma unroll
    for (int j = 0; j < 30; ++j) t1[j] = tanh_f(t1[j]);
    float oacc = b3[0];
    for (int j2 = 0; j2 < 100; ++j2) {
        float a2 = b2s[j2];
        #pragma unroll
        for (int k = 0; k < 30; ++k) a2 += t1[k] * w2s[j2 * 32 + k];
        oacc += tanh_f(a2) * w3s[j2];
    }
    out[pos] = sigm(oacc);
}

// ---------------------------------------------------------------------------
extern "C" void kernel_launch(void* const* d_in, const int* in_sizes, int n_in,
                              void* d_out, int out_size, void* d_ws, size_t ws_size,
                              hipStream_t stream)
{
    const float* x    = (const float*)d_in[0];
    const float* Wih0 = (const float*)d_in[1];
    const float* Whh0 = (const float*)d_in[2];
    const float* bih0 = (const float*)d_in[3];
    const float* bhh0 = (const float*)d_in[4];
    const float* Wih1 = (const float*)d_in[5];
    const float* Whh1 = (const float*)d_in[6];
    const float* bih1 = (const float*)d_in[7];
    const float* bhh1 = (const float*)d_in[8];
    const float* W1   = (const float*)d_in[9];
    const float* b1   = (const float*)d_in[10];
    const float* W2   = (const float*)d_in[11];
    const float* b2   = (const float*)d_in[12];
    const float* W3   = (const float*)d_in[13];
    const float* b3   = (const float*)d_in[14];

    char* ws = (char*)d_ws;
    const size_t OFF_WR0 = 0x000000;   // 768000 B
    const size_t OFF_WG0 = 0x0C0000;   // 76800 B
    const size_t OFF_WR1 = 0x0D4000;   // 768000 B
    const size_t OFF_WG1 = 0x190000;   // 768000 B
    const size_t OFF_B0  = 0x24C000;   // 4800 B
    const size_t OFF_B1  = 0x24E000;   // 4800 B
    const size_t OFF_FLG = 0x250000;   // 2 x 16 x 128 x 4 = 16384 B
    const size_t OFF_HX0 = 0x254000;   // 16 x 10240 x 2 = 327680 B
    const size_t OFF_HX1 = 0x2A4000;   // 327680 B
    const size_t OFF_H0  = 0x300000;   // 41,943,040 B
    const size_t HB      = (size_t)B_ * T_ * HP_ * 2;
    const size_t OFF_H1  = OFF_H0 + HB;
    const size_t NEED    = OFF_H1 + HB;          // 87,031,808 B
    if (ws_size < NEED) return;

    uint32* wr0 = (uint32*)(ws + OFF_WR0);
    uint32* wg0 = (uint32*)(ws + OFF_WG0);
    uint32* wr1 = (uint32*)(ws + OFF_WR1);
    uint32* wg1 = (uint32*)(ws + OFF_WG1);
    float*  b0p = (float*)(ws + OFF_B0);
    float*  b1p = (float*)(ws + OFF_B1);
    int*    flg0 = (int*)(ws + OFF_FLG);
    int*    flg1 = flg0 + 2048;
    unsigned short* hx0 = (unsigned short*)(ws + OFF_HX0);
    unsigned short* hx1 = (unsigned short*)(ws + OFF_HX1);
    unsigned short* h0b = (unsigned short*)(ws + OFF_H0);
    unsigned short* h1b = (unsigned short*)(ws + OFF_H1);

    hipMemsetAsync(ws + OFF_FLG, 0, 16384, stream);   // flags start at epoch 0

    hipLaunchKernelGGL(pack_kernel, dim3(591), dim3(256), 0, stream,
                       Wih0, Whh0, bih0, bhh0, Wih1, Whh1, bih1, bhh1,
                       wr0, wg0, wr1, wg1, b0p, b1p);
    hipLaunchKernelGGL(lstm_rec0, dim3(MEMB_ * 16), dim3(512), 0, stream,
                       x, (const short8*)wr0, (const short8*)wg0, b0p,
                       h0b, hx0, flg0);
    hipLaunchKernelGGL(lstm_rec1, dim3(MEMB_ * 16), dim3(512), 0, stream,
                       h0b, (const short8*)wr1, (const short8*)wg1, b1p,
                       h1b, hx1, flg1);
    hipLaunchKernelGGL(head_kernel, dim3(256), dim3(256), 0, stream,
                       h1b, W1, b1, W2, b2, W3, b3, (float*)d_out);
}

// Round 9
// 2431.413 us; speedup vs baseline: 1.0016x; 1.0016x over previous
//
#include <hip/hip_runtime.h>

#define B_ 256
#define T_ 256
#define H_ 300
#define IN_ 16
#define NT_ 75          // gate tiles (1200/16)
#define KSR_ 10         // recurrent K slabs (300 -> 320)
#define HP_ 320         // padded h row stride (elements)
#define MEMB_ 10        // member blocks per group
#define WPB_ 8          // waves per block (512 threads)

typedef __attribute__((ext_vector_type(8))) short short8;
typedef __attribute__((ext_vector_type(4))) float f32x4;
typedef unsigned int uint32;

union S8U { short8 s; uint32 u[4]; };

__device__ __forceinline__ unsigned short f2bf(float f) {
    uint32 u = __float_as_uint(f);
    u = u + 0x7fffu + ((u >> 16) & 1u);   // RNE
    return (unsigned short)(u >> 16);
}
__device__ __forceinline__ float bf2f(unsigned short h) {
    return __uint_as_float(((uint32)h) << 16);
}
__device__ __forceinline__ float sigm(float x) {
    float e = __expf(-x);
    return __builtin_amdgcn_rcpf(1.f + e);
}
__device__ __forceinline__ float tanh_f(float x) {
    float xc = fminf(fmaxf(x, -15.f), 15.f);
    float e = __expf(2.f * xc);
    return (e - 1.f) * __builtin_amdgcn_rcpf(e + 1.f);
}

// --- asm loads: force the load instruction; residency is enforced by
// amdgpu_waves_per_eu(2,2) (occupancy TARGET = 2 waves/EU -> 256-VGPR
// budget; launch_bounds' min-arg alone does NOT lower the target, which
// is why rounds 4-8 all allocated 60 VGPRs and spilled the weights).
// offset: is 13-bit SIGNED: keep immediates <= 3072, extra bases past 4 KB.
template<int OFF>
__device__ __forceinline__ void gl16(short8& r, const void* p) {
    static_assert(OFF >= 0 && OFF <= 4095, "13-bit signed offset");
    asm volatile("global_load_dwordx4 %0, %1, off offset:%2"
                 : "=v"(r) : "v"(p), "i"(OFF));
}
// IF$ (coherence-point) ops: sc0 sc1, bypass L1/L2, no cache-maintenance
template<int OFF>
__device__ __forceinline__ void gl16c(short8& r, const void* p) {
    static_assert(OFF >= 0 && OFF <= 4095, "13-bit signed offset");
    asm volatile("global_load_dwordx4 %0, %1, off offset:%2 sc0 sc1"
                 : "=v"(r) : "v"(p), "i"(OFF));
}
__device__ __forceinline__ void vm0() {
    asm volatile("s_waitcnt vmcnt(0)" ::: "memory");
}
__device__ __forceinline__ void st2c(unsigned short* p, unsigned short v) {
    uint32 vv = v;
    asm volatile("global_store_short %0, %1, off sc0 sc1" :: "v"(p), "v"(vv) : "memory");
}
__device__ __forceinline__ void st4c(int* p, int v) {
    asm volatile("global_store_dword %0, %1, off sc0 sc1" :: "v"(p), "v"(v) : "memory");
}

// load 10 slabs (1024 B apart) from base p via 3 bases, immediates <= 3072
#define LOAD10(PFX, v0,v1,v2,v3,v4,v5,v6,v7,v8,v9, p)                    \
    do {                                                                 \
        const char* _b0 = (const char*)(p);                              \
        const char* _b1 = _b0 + 4096;                                    \
        const char* _b2 = _b0 + 8192;                                    \
        PFX<0>(v0, _b0);    PFX<1024>(v1, _b0);                          \
        PFX<2048>(v2, _b0); PFX<3072>(v3, _b0);                          \
        PFX<0>(v4, _b1);    PFX<1024>(v5, _b1);                          \
        PFX<2048>(v6, _b1); PFX<3072>(v7, _b1);                          \
        PFX<0>(v8, _b2);    PFX<1024>(v9, _b2);                          \
    } while (0)

#define MF(w_, a_, acc_) acc_ = __builtin_amdgcn_mfma_f32_16x16x32_bf16(w_, a_, acc_, 0, 0, 0)

// ---------------------------------------------------------------------------
// Weight packing into bf16 MFMA A-fragments, gate rows permuted unit-major.
// ---------------------------------------------------------------------------
__device__ __forceinline__ void pack_one(int idx, const float* __restrict__ W,
                                         int K, int KS, uint32* __restrict__ dst)
{
    int lane = idx & 63, ts = idx >> 6;
    int slab = ts % KS, tile = ts / KS;
    int rp = tile * 16 + (lane & 15);
    int jj = rp >> 2, g = rp & 3;
    int r = g * H_ + jj;
    int kb = slab * 32 + (lane >> 4) * 8;
    #pragma unroll
    for (int p = 0; p < 4; ++p) {
        int k0 = kb + 2 * p, k1 = k0 + 1;
        float v0 = (k0 < K) ? W[(size_t)r * K + k0] : 0.f;
        float v1 = (k1 < K) ? W[(size_t)r * K + k1] : 0.f;
        dst[(size_t)idx * 4 + p] = (uint32)f2bf(v0) | ((uint32)f2bf(v1) << 16);
    }
}

__global__ void pack_kernel(const float* __restrict__ Wih0, const float* __restrict__ Whh0,
                            const float* __restrict__ bih0, const float* __restrict__ bhh0,
                            const float* __restrict__ Wih1, const float* __restrict__ Whh1,
                            const float* __restrict__ bih1, const float* __restrict__ bhh1,
                            uint32* __restrict__ wr0, uint32* __restrict__ wg0,
                            uint32* __restrict__ wr1, uint32* __restrict__ wg1,
                            float* __restrict__ b0p, float* __restrict__ b1p)
{
    const int C0 = NT_ * KSR_ * 64;   // 48000
    const int C1 = NT_ * 64;          // 4800
    int id = blockIdx.x * 256 + threadIdx.x;
    if (id < C0) pack_one(id, Whh0, H_, KSR_, wr0);
    else if (id < C0 + C1) pack_one(id - C0, Wih0, IN_, 1, wg0);
    else if (id < 2 * C0 + C1) pack_one(id - C0 - C1, Whh1, H_, KSR_, wr1);
    else if (id < 3 * C0 + C1) pack_one(id - 2 * C0 - C1, Wih1, H_, KSR_, wg1);
    else if (id < 3 * C0 + C1 + 1200) {
        int p = id - 3 * C0 - C1;
        int jj = p >> 2, g = p & 3, r = g * H_ + jj;
        b0p[p] = bih0[r] + bhh0[r];
    } else if (id < 3 * C0 + C1 + 2400) {
        int p = id - 3 * C0 - C1 - 1200;
        int jj = p >> 2, g = p & 3, r = g * H_ + jj;
        b1p[p] = bih1[r] + bhh1[r];
    }
}

// ---------------------------------------------------------------------------
// Layer 0, single dispatch over all 256 steps. 160 blocks x 512 threads.
// blockIdx = member*16 + g; wave owns tile member*8+wave (80 waves/group).
// Whh0 (10 slabs) + Wih0 (1 slab) pinned (256-VGPR budget via waves_per_eu).
// Exchange: per-wave epoch flags + 2-slot fragment buffer, all at IF$.
// ---------------------------------------------------------------------------
__global__ __attribute__((amdgpu_flat_work_group_size(512, 512),
                          amdgpu_waves_per_eu(2, 2)))
void lstm_rec0(
    const float* __restrict__ x, const short8* __restrict__ wr,
    const short8* __restrict__ wxp, const float* __restrict__ bp,
    unsigned short* __restrict__ hrm, unsigned short* __restrict__ hx,
    int* __restrict__ flags)
{
    const int tid = threadIdx.x;
    const int wave = tid >> 6, lane = tid & 63;
    const int g = blockIdx.x & 15, member = blockIdx.x >> 4;
    const int rawwt = member * WPB_ + wave;          // 0..79
    const bool act = rawwt < NT_;
    const int wtile = act ? rawwt : NT_ - 1;
    const int m = lane & 15, oct = lane >> 4;

    // pinned weights
    const short8* wq = wr + (size_t)wtile * (KSR_ * 64) + lane;
    short8 w0, w1, w2, w3, w4, w5, w6, w7, w8, w9, wxv;
    LOAD10(gl16, w0, w1, w2, w3, w4, w5, w6, w7, w8, w9, wq);
    gl16<0>(wxv, wxp + (size_t)wtile * 64 + lane);
    const f32x4 b4 = *(const f32x4*)&bp[wtile * 16 + oct * 4];
    vm0();
    __builtin_amdgcn_sched_barrier(0);

    unsigned short* hxg = hx + (size_t)g * 10240;    // 2 slots x 5120 shorts
    int* fbase = flags + g * 128;
    const int* fp1 = fbase + lane;
    const int* fp2 = fbase + 64 + (lane & 15);
    int* fw = fbase + rawwt;

    const int jj = wtile * 4 + oct;
    const int fragaddr = (((jj >> 5) * 64 + ((jj >> 3) & 3) * 16 + m) << 3) + (jj & 7);
    unsigned short* hxs0 = hxg + fragaddr;
    unsigned short* hxs1 = hxg + 5120 + fragaddr;
    unsigned short* hout = hrm + ((size_t)(g * 16 + m) * T_) * HP_ + jj;
    const float* xrow = x + ((size_t)(g * 16 + m) * T_) * IN_ + (oct & 1) * 8;
    const unsigned short* exb = hxg + lane * 8;

    const short8 z8 = {0, 0, 0, 0, 0, 0, 0, 0};
    short8 a0 = z8, a1 = z8, a2 = z8, a3 = z8, a4 = z8,
           a5 = z8, a6 = z8, a7 = z8, a8 = z8, a9 = z8;
    float c = 0.f;

    #pragma unroll 1
    for (int t = 0; t < T_; ++t) {
        // x slab (plain loads, off critical path)
        const float* xr = xrow + (size_t)t * IN_;
        f32x4 xf0 = *(const f32x4*)xr;
        f32x4 xf1 = *(const f32x4*)(xr + 4);
        S8U xu;
        xu.u[0] = (uint32)f2bf(xf0[0]) | ((uint32)f2bf(xf0[1]) << 16);
        xu.u[1] = (uint32)f2bf(xf0[2]) | ((uint32)f2bf(xf0[3]) << 16);
        xu.u[2] = (uint32)f2bf(xf1[0]) | ((uint32)f2bf(xf1[1]) << 16);
        xu.u[3] = (uint32)f2bf(xf1[2]) | ((uint32)f2bf(xf1[3]) << 16);
        short8 xa = (oct < 2) ? xu.s : z8;

        // pre-poll chain: x contribution
        f32x4 accX = {0.f, 0.f, 0.f, 0.f};
        MF(wxv, xa, accX);

        if (t > 0) {
            // wait for all 80 waves of the group to have published h[t-1]
            int it = 0;
            for (;;) {
                int f1, f2;
                asm volatile("global_load_dword %0, %2, off sc0 sc1\n\t"
                             "global_load_dword %1, %3, off sc0 sc1\n\t"
                             "s_waitcnt vmcnt(0)"
                             : "=&v"(f1), "=&v"(f2) : "v"(fp1), "v"(fp2) : "memory");
                unsigned long long bad = __ballot(f1 < t) | (__ballot(f2 < t) & 0xffffull);
                if (bad == 0) break;
                __builtin_amdgcn_s_sleep(1);
                if (++it > (1 << 22)) break;   // bailout: wrong > hung
            }
            const unsigned short* sb = exb + (size_t)(((t - 1) & 1) * 5120);
            LOAD10(gl16c, a0, a1, a2, a3, a4, a5, a6, a7, a8, a9, sb);
            vm0();
            __builtin_amdgcn_sched_barrier(0);
        }

        f32x4 accA = {0.f, 0.f, 0.f, 0.f}, accB = {0.f, 0.f, 0.f, 0.f};
        MF(w0, a0, accA); MF(w1, a1, accB);
        MF(w2, a2, accA); MF(w3, a3, accB);
        MF(w4, a4, accA); MF(w5, a5, accB);
        MF(w6, a6, accA); MF(w7, a7, accB);
        MF(w8, a8, accA); MF(w9, a9, accB);

        float gi = sigm(accA[0] + accB[0] + accX[0] + b4[0]);
        float gf = sigm(accA[1] + accB[1] + accX[1] + b4[1]);
        float gg = tanh_f(accA[2] + accB[2] + accX[2] + b4[2]);
        float go = sigm(accA[3] + accB[3] + accX[3] + b4[3]);
        float cn = gf * c + gi * gg;
        c = cn;
        unsigned short hb = f2bf(go * tanh_f(cn));
        if (act) {
            st2c((t & 1) ? hxs1 : hxs0, hb);       // exchange (IF$)
            hout[(size_t)t * HP_] = hb;            // row-major for layer 1 (L2)
        }
        vm0();                                     // stores visible at IF$
        if (lane == 0) st4c(fw, t + 1);            // publish epoch
    }
}

// ---------------------------------------------------------------------------
// Layer 1, single dispatch. Same geometry; Whh1 AND Wih1 pinned (80 VGPRs).
// Per step: b-frags (h0, plain/L2, pre-poll) -> acc1 chain overlaps the
// flag wait -> exchange a-frags -> acc0 chain -> epilogue.
// ---------------------------------------------------------------------------
__global__ __attribute__((amdgpu_flat_work_group_size(512, 512),
                          amdgpu_waves_per_eu(2, 2)))
void lstm_rec1(
    const unsigned short* __restrict__ h0rm, const short8* __restrict__ wr,
    const short8* __restrict__ wxq, const float* __restrict__ bp,
    unsigned short* __restrict__ hrm, unsigned short* __restrict__ hx,
    int* __restrict__ flags)
{
    const int tid = threadIdx.x;
    const int wave = tid >> 6, lane = tid & 63;
    const int g = blockIdx.x & 15, member = blockIdx.x >> 4;
    const int rawwt = member * WPB_ + wave;
    const bool act = rawwt < NT_;
    const int wtile = act ? rawwt : NT_ - 1;
    const int m = lane & 15, oct = lane >> 4;

    const short8* wq = wr + (size_t)wtile * (KSR_ * 64) + lane;
    const short8* xq = wxq + (size_t)wtile * (KSR_ * 64) + lane;
    short8 w0, w1, w2, w3, w4, w5, w6, w7, w8, w9;
    short8 x0, x1, x2, x3, x4, x5, x6, x7, x8, x9;
    LOAD10(gl16, w0, w1, w2, w3, w4, w5, w6, w7, w8, w9, wq);
    LOAD10(gl16, x0, x1, x2, x3, x4, x5, x6, x7, x8, x9, xq);
    const f32x4 b4 = *(const f32x4*)&bp[wtile * 16 + oct * 4];
    vm0();
    __builtin_amdgcn_sched_barrier(0);

    unsigned short* hxg = hx + (size_t)g * 10240;
    int* fbase = flags + g * 128;
    const int* fp1 = fbase + lane;
    const int* fp2 = fbase + 64 + (lane & 15);
    int* fw = fbase + rawwt;

    const int jj = wtile * 4 + oct;
    const int fragaddr = (((jj >> 5) * 64 + ((jj >> 3) & 3) * 16 + m) << 3) + (jj & 7);
    unsigned short* hxs0 = hxg + fragaddr;
    unsigned short* hxs1 = hxg + 5120 + fragaddr;
    unsigned short* hout = hrm + ((size_t)(g * 16 + m) * T_) * HP_ + jj;
    const unsigned short* h0b = h0rm + ((size_t)(g * 16 + m) * T_) * HP_ + oct * 8;
    const unsigned short* exb = hxg + lane * 8;

    const short8 z8 = {0, 0, 0, 0, 0, 0, 0, 0};
    short8 a0 = z8, a1 = z8, a2 = z8, a3 = z8, a4 = z8,
           a5 = z8, a6 = z8, a7 = z8, a8 = z8, a9 = z8;
    float c = 0.f;

    #pragma unroll 1
    for (int t = 0; t < T_; ++t) {
        // h0 fragments for this step (plain, L2-served; ready since kernel start)
        const unsigned short* br = h0b + (size_t)t * HP_;
        short8 b0 = *(const short8*)(br);
        short8 b1 = *(const short8*)(br + 32);
        short8 b2 = *(const short8*)(br + 64);
        short8 b3 = *(const short8*)(br + 96);
        short8 b4f = *(const short8*)(br + 128);
        short8 b5 = *(const short8*)(br + 160);
        short8 b6 = *(const short8*)(br + 192);
        short8 b7 = *(const short8*)(br + 224);
        short8 b8 = *(const short8*)(br + 256);
        short8 b9 = *(const short8*)(br + 288);

        // pre-poll chain: Wih1 @ h0 (independent of the recurrence)
        f32x4 acc1 = {0.f, 0.f, 0.f, 0.f};
        MF(x0, b0, acc1); MF(x1, b1, acc1); MF(x2, b2, acc1);
        MF(x3, b3, acc1); MF(x4, b4f, acc1); MF(x5, b5, acc1);
        MF(x6, b6, acc1); MF(x7, b7, acc1); MF(x8, b8, acc1);
        MF(x9, b9, acc1);

        if (t > 0) {
            int it = 0;
            for (;;) {
                int f1, f2;
                asm volatile("global_load_dword %0, %2, off sc0 sc1\n\t"
                             "global_load_dword %1, %3, off sc0 sc1\n\t"
                             "s_waitcnt vmcnt(0)"
                             : "=&v"(f1), "=&v"(f2) : "v"(fp1), "v"(fp2) : "memory");
                unsigned long long bad = __ballot(f1 < t) | (__ballot(f2 < t) & 0xffffull);
                if (bad == 0) break;
                __builtin_amdgcn_s_sleep(1);
                if (++it > (1 << 22)) break;
            }
            const unsigned short* sb = exb + (size_t)(((t - 1) & 1) * 5120);
            LOAD10(gl16c, a0, a1, a2, a3, a4, a5, a6, a7, a8, a9, sb);
            vm0();
            __builtin_amdgcn_sched_barrier(0);
        }

        f32x4 accA = {0.f, 0.f, 0.f, 0.f}, accB = {0.f, 0.f, 0.f, 0.f};
        MF(w0, a0, accA); MF(w1, a1, accB);
        MF(w2, a2, accA); MF(w3, a3, accB);
        MF(w4, a4, accA); MF(w5, a5, accB);
        MF(w6, a6, accA); MF(w7, a7, accB);
        MF(w8, a8, accA); MF(w9, a9, accB);

        float gi = sigm(accA[0] + accB[0] + acc1[0] + b4[0]);
        float gf = sigm(accA[1] + accB[1] + acc1[1] + b4[1]);
        float gg = tanh_f(accA[2] + accB[2] + acc1[2] + b4[2]);
        float go = sigm(accA[3] + accB[3] + acc1[3] + b4[3]);
        float cn = gf * c + gi * gg;
        c = cn;
        unsigned short hb = f2bf(go * tanh_f(cn));
        if (act) {
            st2c((t & 1) ? hxs1 : hxs0, hb);
            hout[(size_t)t * HP_] = hb;            // row-major for head
        }
        vm0();
        if (lane == 0) st4c(fw, t + 1);
    }
}

// ---------------------------------------------------------------------------
// MLP head: W1/W2/W3 staged in LDS (broadcast reads), one thread per position.
// ---------------------------------------------------------------------------
__global__ __launch_bounds__(256) void head_kernel(
    const unsigned short* __restrict__ h1,
    const float* __restrict__ W1, const float* __restrict__ b1,
    const float* __restrict__ W2, const float* __restrict__ b2,
    const float* __restrict__ W3, const float* __restrict__ b3,
    float* __restrict__ out)
{
    __shared__ float w1s[9000];     // 30x300
    __shared__ float w2s[3200];     // 100x32 (padded)
    __shared__ float w3s[100];
    __shared__ float b1s[30];
    __shared__ float b2s[100];
    const int tid = threadIdx.x;
    for (int i = tid; i < 9000; i += 256) w1s[i] = W1[i];
    for (int i = tid; i < 3000; i += 256) w2s[(i / 30) * 32 + (i % 30)] = W2[i];
    if (tid < 100) { w3s[tid] = W3[tid]; b2s[tid] = b2[tid]; }
    if (tid < 30)  b1s[tid] = b1[tid];
    __syncthreads();

    const int pos = blockIdx.x * 256 + tid;
    const unsigned short* hr = h1 + (size_t)pos * HP_;
    float t1[30];
    #pragma unroll
    for (int j = 0; j < 30; ++j) t1[j] = b1s[j];
    for (int kc = 0; kc < H_; kc += 4) {
        uint32 u0 = *(const uint32*)(hr + kc);
        uint32 u1 = *(const uint32*)(hr + kc + 2);
        float h0v = bf2f((unsigned short)(u0 & 0xffffu));
        float h1v = bf2f((unsigned short)(u0 >> 16));
        float h2v = bf2f((unsigned short)(u1 & 0xffffu));
        float h3v = bf2f((unsigned short)(u1 >> 16));
        #pragma unroll
        for (int j = 0; j < 30; ++j) {
            const f32x4 wv = *(const f32x4*)&w1s[j * H_ + kc];
            t1[j] += h0v * wv[0] + h1v * wv[1] + h2v * wv[2] + h3v * wv[3];
        }
    }
    #pragma unroll
    for (int j = 0; j < 30; ++j) t1[j] = tanh_f(t1[j]);
    float oacc = b3[0];
    for (int j2 = 0; j2 < 100; ++j2) {
        float a2 = b2s[j2];
        #pragma unroll
        for (int k = 0; k < 30; ++k) a2 += t1[k] * w2s[j2 * 32 + k];
        oacc += tanh_f(a2) * w3s[j2];
    }
    out[pos] = sigm(oacc);
}

// ---------------------------------------------------------------------------
extern "C" void kernel_launch(void* const* d_in, const int* in_sizes, int n_in,
                              void* d_out, int out_size, void* d_ws, size_t ws_size,
                              hipStream_t stream)
{
    const float* x    = (const float*)d_in[0];
    const float* Wih0 = (const float*)d_in[1];
    const float* Whh0 = (const float*)d_in[2];
    const float* bih0 = (const float*)d_in[3];
    const float* bhh0 = (const float*)d_in[4];
    const float* Wih1 = (const float*)d_in[5];
    const float* Whh1 = (const float*)d_in[6];
    const float* bih1 = (const float*)d_in[7];
    const float* bhh1 = (const float*)d_in[8];
    const float* W1   = (const float*)d_in[9];
    const float* b1   = (const float*)d_in[10];
    const float* W2   = (const float*)d_in[11];
    const float* b2   = (const float*)d_in[12];
    const float* W3   = (const float*)d_in[13];
    const float* b3   = (const float*)d_in[14];

    char* ws = (char*)d_ws;
    const size_t OFF_WR0 = 0x000000;   // 768000 B
    const size_t OFF_WG0 = 0x0C0000;   // 76800 B
    const size_t OFF_WR1 = 0x0D4000;   // 768000 B
    const size_t OFF_WG1 = 0x190000;   // 768000 B
    const size_t OFF_B0  = 0x24C000;   // 4800 B
    const size_t OFF_B1  = 0x24E000;   // 4800 B
    const size_t OFF_FLG = 0x250000;   // 2 x 16 x 128 x 4 = 16384 B
    const size_t OFF_HX0 = 0x254000;   // 16 x 10240 x 2 = 327680 B
    const size_t OFF_HX1 = 0x2A4000;   // 327680 B
    const size_t OFF_H0  = 0x300000;   // 41,943,040 B
    const size_t HB      = (size_t)B_ * T_ * HP_ * 2;
    const size_t OFF_H1  = OFF_H0 + HB;
    const size_t NEED    = OFF_H1 + HB;          // 87,031,808 B
    if (ws_size < NEED) return;

    uint32* wr0 = (uint32*)(ws + OFF_WR0);
    uint32* wg0 = (uint32*)(ws + OFF_WG0);
    uint32* wr1 = (uint32*)(ws + OFF_WR1);
    uint32* wg1 = (uint32*)(ws + OFF_WG1);
    float*  b0p = (float*)(ws + OFF_B0);
    float*  b1p = (float*)(ws + OFF_B1);
    int*    flg0 = (int*)(ws + OFF_FLG);
    int*    flg1 = flg0 + 2048;
    unsigned short* hx0 = (unsigned short*)(ws + OFF_HX0);
    unsigned short* hx1 = (unsigned short*)(ws + OFF_HX1);
    unsigned short* h0b = (unsigned short*)(ws + OFF_H0);
    unsigned short* h1b = (unsigned short*)(ws + OFF_H1);

    hipMemsetAsync(ws + OFF_FLG, 0, 16384, stream);   // flags start at epoch 0

    hipLaunchKernelGGL(pack_kernel, dim3(591), dim3(256), 0, stream,
                       Wih0, Whh0, bih0, bhh0, Wih1, Whh1, bih1, bhh1,
                       wr0, wg0, wr1, wg1, b0p, b1p);
    hipLaunchKernelGGL(lstm_rec0, dim3(MEMB_ * 16), dim3(512), 0, stream,
                       x, (const short8*)wr0, (const short8*)wg0, b0p,
                       h0b, hx0, flg0);
    hipLaunchKernelGGL(lstm_rec1, dim3(MEMB_ * 16), dim3(512), 0, stream,
                       h0b, (const short8*)wr1, (const short8*)wg1, b1p,
                       h1b, hx1, flg1);
    hipLaunchKernelGGL(head_kernel, dim3(256), dim3(256), 0, stream,
                       h1b, W1, b1, W2, b2, W3, b3, (float*)d_out);
}

// Round 10
// 1883.544 us; speedup vs baseline: 1.2930x; 1.2909x over previous
//
#include <hip/hip_runtime.h>

#define B_ 256
#define T_ 256
#define H_ 300
#define IN_ 16
#define NT_ 75          // gate tiles (1200/16)
#define KSR_ 10         // recurrent K slabs (300 -> 320)
#define HP_ 320         // padded h row stride (elements)
#define MEMB_ 8         // member blocks per group
#define WPB_ 10         // waves per block (640 threads)

typedef __attribute__((ext_vector_type(8))) short short8;
typedef __attribute__((ext_vector_type(4))) float f32x4;
typedef unsigned int uint32;

union S8U { short8 s; uint32 u[4]; };

__device__ __forceinline__ unsigned short f2bf(float f) {
    uint32 u = __float_as_uint(f);
    u = u + 0x7fffu + ((u >> 16) & 1u);   // RNE
    return (unsigned short)(u >> 16);
}
__device__ __forceinline__ float bf2f(unsigned short h) {
    return __uint_as_float(((uint32)h) << 16);
}
__device__ __forceinline__ float sigm(float x) {
    float e = __expf(-x);
    return __builtin_amdgcn_rcpf(1.f + e);
}
__device__ __forceinline__ float tanh_f(float x) {
    float xc = fminf(fmaxf(x, -15.f), 15.f);
    float e = __expf(2.f * xc);
    return (e - 1.f) * __builtin_amdgcn_rcpf(e + 1.f);
}

// IF$ (coherence-point) ops: sc0 sc1 bypass L1/L2 -> coherent across XCDs
// with zero cache-maintenance instructions. Used ONLY for the per-step
// exchange (h fragments, counter); bulk data goes through normal caches.
__device__ __forceinline__ short8 ld16c(const void* p) {
    short8 r;
    asm volatile("global_load_dwordx4 %0, %1, off sc0 sc1"
                 : "=v"(r) : "v"(p));
    return r;
}
__device__ __forceinline__ int ldcnt(const int* p) {
    int r;
    asm volatile("global_load_dword %0, %1, off sc0 sc1\n\ts_waitcnt vmcnt(0)"
                 : "=v"(r) : "v"(p) : "memory");
    return r;
}
__device__ __forceinline__ void st2c(unsigned short* p, unsigned short v) {
    uint32 vv = v;
    asm volatile("global_store_short %0, %1, off sc0 sc1" :: "v"(p), "v"(vv) : "memory");
}
__device__ __forceinline__ void atomic_inc_cg(int* p) {
    int one = 1;
    asm volatile("global_atomic_add %0, %1, off sc1" :: "v"(p), "v"(one) : "memory");
}
__device__ __forceinline__ void vm0() {
    asm volatile("s_waitcnt vmcnt(0)" ::: "memory");
}

#define MF(w_, a_, acc_) acc_ = __builtin_amdgcn_mfma_f32_16x16x32_bf16(w_, a_, acc_, 0, 0, 0)

// ---------------------------------------------------------------------------
// Weight packing into bf16 MFMA A-fragments, gate rows permuted unit-major.
// ---------------------------------------------------------------------------
__device__ __forceinline__ void pack_one(int idx, const float* __restrict__ W,
                                         int K, int KS, uint32* __restrict__ dst)
{
    int lane = idx & 63, ts = idx >> 6;
    int slab = ts % KS, tile = ts / KS;
    int rp = tile * 16 + (lane & 15);
    int jj = rp >> 2, g = rp & 3;
    int r = g * H_ + jj;
    int kb = slab * 32 + (lane >> 4) * 8;
    #pragma unroll
    for (int p = 0; p < 4; ++p) {
        int k0 = kb + 2 * p, k1 = k0 + 1;
        float v0 = (k0 < K) ? W[(size_t)r * K + k0] : 0.f;
        float v1 = (k1 < K) ? W[(size_t)r * K + k1] : 0.f;
        dst[(size_t)idx * 4 + p] = (uint32)f2bf(v0) | ((uint32)f2bf(v1) << 16);
    }
}

__global__ void pack_kernel(const float* __restrict__ Wih0, const float* __restrict__ Whh0,
                            const float* __restrict__ bih0, const float* __restrict__ bhh0,
                            const float* __restrict__ Wih1, const float* __restrict__ Whh1,
                            const float* __restrict__ bih1, const float* __restrict__ bhh1,
                            uint32* __restrict__ wr0, uint32* __restrict__ wg0,
                            uint32* __restrict__ wr1, uint32* __restrict__ wg1,
                            float* __restrict__ b0p, float* __restrict__ b1p)
{
    const int C0 = NT_ * KSR_ * 64;   // 48000
    const int C1 = NT_ * 64;          // 4800
    int id = blockIdx.x * 256 + threadIdx.x;
    if (id < C0) pack_one(id, Whh0, H_, KSR_, wr0);
    else if (id < C0 + C1) pack_one(id - C0, Wih0, IN_, 1, wg0);
    else if (id < 2 * C0 + C1) pack_one(id - C0 - C1, Whh1, H_, KSR_, wr1);
    else if (id < 3 * C0 + C1) pack_one(id - 2 * C0 - C1, Wih1, H_, KSR_, wg1);
    else if (id < 3 * C0 + C1 + 1200) {
        int p = id - 3 * C0 - C1;
        int jj = p >> 2, g = p & 3, r = g * H_ + jj;
        b0p[p] = bih0[r] + bhh0[r];
    } else if (id < 3 * C0 + C1 + 2400) {
        int p = id - 3 * C0 - C1 - 1200;
        int jj = p >> 2, g = p & 3, r = g * H_ + jj;
        b1p[p] = bih1[r] + bhh1[r];
    }
}

// ---------------------------------------------------------------------------
// Recurrent layer, single dispatch. 128 blocks x 640 threads.
// blockIdx = member*16 + g; wave w owns tile member*10+w (80 waves/group,
// 75 active). Whh slice lives in LDS (100 KB/block, loaded once).
// Per step: [pre-poll independent chain] -> tid0 polls IF$ counter ->
// barrier -> each wave stages ONE slab (1 KB) IF$->LDS -> barrier ->
// ds_read w+a frags -> 10 MFMA -> epilogue -> IF$ store -> barrier ->
// tid0 atomic-inc. IF$ read traffic: 80 KB/group/step (vs 750 KB when
// every wave loads the full vector uncached -- round 7's 4.6 us/step).
// ---------------------------------------------------------------------------
template<int LAYER>
__global__ __launch_bounds__(640) void lstm_rec(
    const void* __restrict__ inptr, const short8* __restrict__ wr,
    const short8* __restrict__ wx, const float* __restrict__ bp,
    unsigned short* __restrict__ hrm, unsigned short* __restrict__ hx,
    int* __restrict__ cnt)
{
    __shared__ short8 wlds[WPB_ * KSR_ * 64];   // 100 KB: this block's Whh tiles
    __shared__ short8 alds[KSR_ * 64];          // 10 KB: staged h fragments

    const int tid = threadIdx.x;
    const int wave = tid >> 6, lane = tid & 63;
    const int g = blockIdx.x & 15, member = blockIdx.x >> 4;
    const int rawwt = member * WPB_ + wave;      // 0..79
    const bool act = rawwt < NT_;
    const int wtile = act ? rawwt : NT_ - 1;
    const int m = lane & 15, oct = lane >> 4;

    // ---- one-time init: weights -> LDS (wr is allocated for 80 tiles), a=0
    {
        const short8* wsrc = wr + (size_t)member * (WPB_ * KSR_ * 64);
        for (int i = tid; i < WPB_ * KSR_ * 64; i += 640) wlds[i] = wsrc[i];
        short8 z = {0, 0, 0, 0, 0, 0, 0, 0};
        if (tid < KSR_ * 64) alds[tid] = z;
    }

    // layer-0 x-weights: 1 slab per tile, loop-invariant in registers
    short8 wxv;
    if constexpr (LAYER == 0) wxv = wx[(size_t)wtile * 64 + lane];
    const f32x4 b4 = *(const f32x4*)&bp[wtile * 16 + oct * 4];

    unsigned short* hxg = hx + (size_t)g * 10240;      // 2 slots x 5120 shorts
    int* cg = cnt + g * 16;

    const int jj = wtile * 4 + oct;
    const int fragaddr = (((jj >> 5) * 64 + ((jj >> 3) & 3) * 16 + m) << 3) + (jj & 7);
    unsigned short* hxs0 = hxg + fragaddr;
    unsigned short* hxs1 = hxg + 5120 + fragaddr;
    unsigned short* hout = hrm + ((size_t)(g * 16 + m) * T_) * HP_ + jj;
    const float* xrow = (LAYER == 0)
        ? ((const float*)inptr + ((size_t)(g * 16 + m) * T_) * IN_ + (oct & 1) * 8)
        : nullptr;
    const unsigned short* h0b = (LAYER == 1)
        ? ((const unsigned short*)inptr + ((size_t)(g * 16 + m) * T_) * HP_ + oct * 8)
        : nullptr;
    const short8* wl = &wlds[wave * (KSR_ * 64) + lane];
    const short8* al = &alds[lane];
    const short8 z8 = {0, 0, 0, 0, 0, 0, 0, 0};

    __syncthreads();   // wlds/alds ready

    float c = 0.f;

    #pragma unroll 1
    for (int t = 0; t < T_; ++t) {
        // ---- pre-poll independent chain (off the serial critical path)
        f32x4 accX = {0.f, 0.f, 0.f, 0.f};
        if constexpr (LAYER == 0) {
            const float* xr = xrow + (size_t)t * IN_;
            f32x4 xf0 = *(const f32x4*)xr;
            f32x4 xf1 = *(const f32x4*)(xr + 4);
            S8U xu;
            xu.u[0] = (uint32)f2bf(xf0[0]) | ((uint32)f2bf(xf0[1]) << 16);
            xu.u[1] = (uint32)f2bf(xf0[2]) | ((uint32)f2bf(xf0[3]) << 16);
            xu.u[2] = (uint32)f2bf(xf1[0]) | ((uint32)f2bf(xf1[1]) << 16);
            xu.u[3] = (uint32)f2bf(xf1[2]) | ((uint32)f2bf(xf1[3]) << 16);
            short8 xa = (oct < 2) ? xu.s : z8;
            MF(wxv, xa, accX);
        } else {
            const unsigned short* br = h0b + (size_t)t * HP_;
            const short8* xq = wx + (size_t)wtile * (KSR_ * 64) + lane;
            #pragma unroll
            for (int s = 0; s < KSR_; ++s) {
                short8 bf = *(const short8*)(br + s * 32);   // shared by block -> L1
                MF(xq[s * 64], bf, accX);                    // Wih1 stream -> L2
            }
        }

        // ---- wait for all members to have published h[t-1], stage to LDS
        if (t > 0) {
            if (tid == 0) {
                const int target = MEMB_ * t;
                int it = 0;
                while (ldcnt(cg) < target) {
                    __builtin_amdgcn_s_sleep(1);
                    if (++it > (1 << 22)) break;   // bailout: wrong > hung
                }
            }
            __syncthreads();
            {   // wave w stages slab w (64 lanes x 16 B = 1 KB)
                const unsigned short* sp = hxg + ((t - 1) & 1) * 5120
                                         + wave * 512 + lane * 8;
                short8 v = ld16c(sp);
                vm0();
                alds[wave * 64 + lane] = v;
            }
            __syncthreads();
        }

        // ---- recurrent MFMA from LDS (weights + staged h)
        f32x4 accA = {0.f, 0.f, 0.f, 0.f}, accB = {0.f, 0.f, 0.f, 0.f};
        #pragma unroll
        for (int s = 0; s < KSR_; s += 2) {
            MF(wl[s * 64],       al[s * 64],       accA);
            MF(wl[(s + 1) * 64], al[(s + 1) * 64], accB);
        }

        float gi = sigm(accA[0] + accB[0] + accX[0] + b4[0]);
        float gf = sigm(accA[1] + accB[1] + accX[1] + b4[1]);
        float gg = tanh_f(accA[2] + accB[2] + accX[2] + b4[2]);
        float go = sigm(accA[3] + accB[3] + accX[3] + b4[3]);
        float cn = gf * c + gi * gg;
        c = cn;
        unsigned short hb = f2bf(go * tanh_f(cn));
        if (act) {
            st2c((t & 1) ? hxs1 : hxs0, hb);       // exchange (IF$)
            hout[(size_t)t * HP_] = hb;            // row-major (L2) for next stage
        }
        vm0();                                     // stores visible before arrive
        __syncthreads();                           // whole block done with step t
        if (tid == 0) atomic_inc_cg(cg);
    }
}

// ---------------------------------------------------------------------------
// MLP head: W1/W2/W3 staged in LDS (broadcast reads), one thread per position.
// ---------------------------------------------------------------------------
__global__ __launch_bounds__(256) void head_kernel(
    const unsigned short* __restrict__ h1,
    const float* __restrict__ W1, const float* __restrict__ b1,
    const float* __restrict__ W2, const float* __restrict__ b2,
    const float* __restrict__ W3, const float* __restrict__ b3,
    float* __restrict__ out)
{
    __shared__ float w1s[9000];     // 30x300
    __shared__ float w2s[3200];     // 100x32 (padded)
    __shared__ float w3s[100];
    __shared__ float b1s[30];
    __shared__ float b2s[100];
    const int tid = threadIdx.x;
    for (int i = tid; i < 9000; i += 256) w1s[i] = W1[i];
    for (int i = tid; i < 3000; i += 256) w2s[(i / 30) * 32 + (i % 30)] = W2[i];
    if (tid < 100) { w3s[tid] = W3[tid]; b2s[tid] = b2[tid]; }
    if (tid < 30)  b1s[tid] = b1[tid];
    __syncthreads();

    const int pos = blockIdx.x * 256 + tid;
    const unsigned short* hr = h1 + (size_t)pos * HP_;
    float t1[30];
    #pragma unroll
    for (int j = 0; j < 30; ++j) t1[j] = b1s[j];
    for (int kc = 0; kc < H_; kc += 4) {
        uint32 u0 = *(const uint32*)(hr + kc);
        uint32 u1 = *(const uint32*)(hr + kc + 2);
        float h0v = bf2f((unsigned short)(u0 & 0xffffu));
        float h1v = bf2f((unsigned short)(u0 >> 16));
        float h2v = bf2f((unsigned short)(u1 & 0xffffu));
        float h3v = bf2f((unsigned short)(u1 >> 16));
        #pragma unroll
        for (int j = 0; j < 30; ++j) {
            const f32x4 wv = *(const f32x4*)&w1s[j * H_ + kc];
            t1[j] += h0v * wv[0] + h1v * wv[1] + h2v * wv[2] + h3v * wv[3];
        }
    }
    #pragma unroll
    for (int j = 0; j < 30; ++j) t1[j] = tanh_f(t1[j]);
    float oacc = b3[0];
    for (int j2 = 0; j2 < 100; ++j2) {
        float a2 = b2s[j2];
        #pragma unroll
        for (int k = 0; k < 30; ++k) a2 += t1[k] * w2s[j2 * 32 + k];
        oacc += tanh_f(a2) * w3s[j2];
    }
    out[pos] = sigm(oacc);
}

// ---------------------------------------------------------------------------
extern "C" void kernel_launch(void* const* d_in, const int* in_sizes, int n_in,
                              void* d_out, int out_size, void* d_ws, size_t ws_size,
                              hipStream_t stream)
{
    const float* x    = (const float*)d_in[0];
    const float* Wih0 = (const float*)d_in[1];
    const float* Whh0 = (const float*)d_in[2];
    const float* bih0 = (const float*)d_in[3];
    const float* bhh0 = (const float*)d_in[4];
    const float* Wih1 = (const float*)d_in[5];
    const float* Whh1 = (const float*)d_in[6];
    const float* bih1 = (const float*)d_in[7];
    const float* bhh1 = (const float*)d_in[8];
    const float* W1   = (const float*)d_in[9];
    const float* b1   = (const float*)d_in[10];
    const float* W2   = (const float*)d_in[11];
    const float* b2   = (const float*)d_in[12];
    const float* W3   = (const float*)d_in[13];
    const float* b3   = (const float*)d_in[14];

    // buffers sized for 80 tiles so member-7 blocks can bulk-copy safely
    char* ws = (char*)d_ws;
    const size_t OFF_WR0 = 0x000000;   // 80*640*16 = 819200 B
    const size_t OFF_WG0 = 0x0D0000;   // 80*64*16  =  81920 B
    const size_t OFF_WR1 = 0x0E8000;   // 819200 B
    const size_t OFF_WG1 = 0x1B0000;   // 819200 B
    const size_t OFF_B0  = 0x280000;   // 4800 B
    const size_t OFF_B1  = 0x282000;   // 4800 B
    const size_t OFF_CNT = 0x284000;   // 2 x 16 x 16 x 4 B
    const size_t OFF_HX0 = 0x290000;   // 16 x 10240 x 2 = 327680 B
    const size_t OFF_HX1 = 0x2E0000;   // 327680 B
    const size_t OFF_H0  = 0x400000;   // 41,943,040 B
    const size_t HB      = (size_t)B_ * T_ * HP_ * 2;
    const size_t OFF_H1  = OFF_H0 + HB;
    const size_t NEED    = OFF_H1 + HB;          // ~88 MB
    if (ws_size < NEED) return;

    uint32* wr0 = (uint32*)(ws + OFF_WR0);
    uint32* wg0 = (uint32*)(ws + OFF_WG0);
    uint32* wr1 = (uint32*)(ws + OFF_WR1);
    uint32* wg1 = (uint32*)(ws + OFF_WG1);
    float*  b0p = (float*)(ws + OFF_B0);
    float*  b1p = (float*)(ws + OFF_B1);
    int*    cnt0 = (int*)(ws + OFF_CNT);
    int*    cnt1 = cnt0 + 256;
    unsigned short* hx0 = (unsigned short*)(ws + OFF_HX0);
    unsigned short* hx1 = (unsigned short*)(ws + OFF_HX1);
    unsigned short* h0b = (unsigned short*)(ws + OFF_H0);
    unsigned short* h1b = (unsigned short*)(ws + OFF_H1);

    hipMemsetAsync(ws + OFF_CNT, 0, 4096, stream);   // counters -> epoch 0

    hipLaunchKernelGGL(pack_kernel, dim3(591), dim3(256), 0, stream,
                       Wih0, Whh0, bih0, bhh0, Wih1, Whh1, bih1, bhh1,
                       wr0, wg0, wr1, wg1, b0p, b1p);
    hipLaunchKernelGGL((lstm_rec<0>), dim3(MEMB_ * 16), dim3(640), 0, stream,
                       (const void*)x, (const short8*)wr0, (const short8*)wg0,
                       b0p, h0b, hx0, cnt0);
    hipLaunchKernelGGL((lstm_rec<1>), dim3(MEMB_ * 16), dim3(640), 0, stream,
                       (const void*)h0b, (const short8*)wr1, (const short8*)wg1,
                       b1p, h1b, hx1, cnt1);
    hipLaunchKernelGGL(head_kernel, dim3(256), dim3(256), 0, stream,
                       h1b, W1, b1, W2, b2, W3, b3, (float*)d_out);
}

// Round 11
// 1029.219 us; speedup vs baseline: 2.3662x; 1.8301x over previous
//
#include <hip/hip_runtime.h>

#define B_ 256
#define T_ 256
#define H_ 300
#define IN_ 16
#define NT_ 75          // gate tiles (1200/16)
#define KSR_ 10         // recurrent K slabs (300 -> 320)
#define HP_ 320         // padded h row stride (elements)
#define MEMB_ 8         // member blocks per group per layer
#define WPB_ 10         // waves per block (640 threads)

typedef __attribute__((ext_vector_type(8))) short short8;
typedef __attribute__((ext_vector_type(4))) float f32x4;
typedef unsigned int uint32;

union S8U { short8 s; uint32 u[4]; };

__device__ __forceinline__ unsigned short f2bf(float f) {
    uint32 u = __float_as_uint(f);
    u = u + 0x7fffu + ((u >> 16) & 1u);   // RNE
    return (unsigned short)(u >> 16);
}
__device__ __forceinline__ float bf2f(unsigned short h) {
    return __uint_as_float(((uint32)h) << 16);
}
__device__ __forceinline__ float sigm(float x) {
    float e = __expf(-x);
    return __builtin_amdgcn_rcpf(1.f + e);
}
__device__ __forceinline__ float tanh_f(float x) {
    float xc = fminf(fmaxf(x, -15.f), 15.f);
    float e = __expf(2.f * xc);
    return (e - 1.f) * __builtin_amdgcn_rcpf(e + 1.f);
}

// IF$ (coherence-point) ops: sc0 sc1 bypass L1/L2 -> coherent across XCDs,
// zero cache-maintenance. Used ONLY for the per-step exchange.
__device__ __forceinline__ short8 ld16c(const void* p) {
    short8 r;
    asm volatile("global_load_dwordx4 %0, %1, off sc0 sc1"
                 : "=v"(r) : "v"(p));
    return r;
}
__device__ __forceinline__ void st2c(unsigned short* p, unsigned short v) {
    uint32 vv = v;
    asm volatile("global_store_short %0, %1, off sc0 sc1" :: "v"(p), "v"(vv) : "memory");
}
__device__ __forceinline__ void atomic_inc_cg(int* p) {
    int one = 1;
    asm volatile("global_atomic_add %0, %1, off sc1" :: "v"(p), "v"(one) : "memory");
}
__device__ __forceinline__ void vm0() {
    asm volatile("s_waitcnt vmcnt(0)" ::: "memory");
}
// dual-counter poll (one IF$ round trip per iteration)
__device__ __forceinline__ void poll2(const int* p0, const int* p1, int ta, int tb) {
    int it = 0;
    for (;;) {
        int c0, c1;
        asm volatile("global_load_dword %0, %2, off sc0 sc1\n\t"
                     "global_load_dword %1, %3, off sc0 sc1\n\t"
                     "s_waitcnt vmcnt(0)"
                     : "=&v"(c0), "=&v"(c1) : "v"(p0), "v"(p1) : "memory");
        if (c0 >= ta && c1 >= tb) break;
        __builtin_amdgcn_s_sleep(1);
        if (++it > (1 << 22)) break;   // bailout: wrong > hung
    }
}

#define MF(w_, a_, acc_) acc_ = __builtin_amdgcn_mfma_f32_16x16x32_bf16(w_, a_, acc_, 0, 0, 0)

// ---------------------------------------------------------------------------
// Weight packing into bf16 MFMA A-fragments, gate rows permuted unit-major.
// ---------------------------------------------------------------------------
__device__ __forceinline__ void pack_one(int idx, const float* __restrict__ W,
                                         int K, int KS, uint32* __restrict__ dst)
{
    int lane = idx & 63, ts = idx >> 6;
    int slab = ts % KS, tile = ts / KS;
    int rp = tile * 16 + (lane & 15);
    int jj = rp >> 2, g = rp & 3;
    int r = g * H_ + jj;
    int kb = slab * 32 + (lane >> 4) * 8;
    #pragma unroll
    for (int p = 0; p < 4; ++p) {
        int k0 = kb + 2 * p, k1 = k0 + 1;
        float v0 = (k0 < K) ? W[(size_t)r * K + k0] : 0.f;
        float v1 = (k1 < K) ? W[(size_t)r * K + k1] : 0.f;
        dst[(size_t)idx * 4 + p] = (uint32)f2bf(v0) | ((uint32)f2bf(v1) << 16);
    }
}

__global__ void pack_kernel(const float* __restrict__ Wih0, const float* __restrict__ Whh0,
                            const float* __restrict__ bih0, const float* __restrict__ bhh0,
                            const float* __restrict__ Wih1, const float* __restrict__ Whh1,
                            const float* __restrict__ bih1, const float* __restrict__ bhh1,
                            uint32* __restrict__ wr0, uint32* __restrict__ wg0,
                            uint32* __restrict__ wr1, uint32* __restrict__ wg1,
                            float* __restrict__ b0p, float* __restrict__ b1p)
{
    const int C0 = NT_ * KSR_ * 64;   // 48000
    const int C1 = NT_ * 64;          // 4800
    int id = blockIdx.x * 256 + threadIdx.x;
    if (id < C0) pack_one(id, Whh0, H_, KSR_, wr0);
    else if (id < C0 + C1) pack_one(id - C0, Wih0, IN_, 1, wg0);
    else if (id < 2 * C0 + C1) pack_one(id - C0 - C1, Whh1, H_, KSR_, wr1);
    else if (id < 3 * C0 + C1) pack_one(id - 2 * C0 - C1, Wih1, H_, KSR_, wg1);
    else if (id < 3 * C0 + C1 + 1200) {
        int p = id - 3 * C0 - C1;
        int jj = p >> 2, g = p & 3, r = g * H_ + jj;
        b0p[p] = bih0[r] + bhh0[r];
    } else if (id < 3 * C0 + C1 + 2400) {
        int p = id - 3 * C0 - C1 - 1200;
        int jj = p >> 2, g = p & 3, r = g * H_ + jj;
        b1p[p] = bih1[r] + bhh1[r];
    }
}

// ---------------------------------------------------------------------------
// BOTH LSTM layers in one dispatch, software-pipelined: 256 blocks x 640.
// blocks 0..127: layer 0 (member*16+g); 128..255: layer 1.
// Layer 0 publishes h0[t] to a 4-slot IF$ ring; layer 1 (lagging 1 step)
// consumes h0[t] + its own h1[t-1] 2-slot ring. Serial chain: 257 steps
// instead of 512. Back-pressure: layer 0 step t overwrites slot t&3 only
// after layer 1 consumed h0[t-4] (cnt1 >= 8*(t-3)).
// Whh lives in LDS (100 KB, loaded once). Wih1 streams from L2 (constant
// addresses, L2-hot). 122.9 KB LDS -> 1 block/CU -> 256 blocks co-resident.
// ---------------------------------------------------------------------------
__global__ __launch_bounds__(640) void lstm_dual(
    const float* __restrict__ x,
    const short8* __restrict__ wr0, const short8* __restrict__ wg0,
    const short8* __restrict__ wr1, const short8* __restrict__ wg1,
    const float* __restrict__ b0p, const float* __restrict__ b1p,
    unsigned short* __restrict__ h1rm,
    unsigned short* __restrict__ ring0, unsigned short* __restrict__ ring1,
    int* __restrict__ cnt)
{
    __shared__ short8 wlds[WPB_ * KSR_ * 64];   // 100 KB: Whh tiles
    __shared__ short8 alds[KSR_ * 64];          // 10 KB: own-layer h state
    __shared__ short8 a0lds[KSR_ * 64];         // 10 KB: h0[t] (layer 1 only)

    const int tid = threadIdx.x;
    const int wave = tid >> 6, lane = tid & 63;
    const int layer = (int)(blockIdx.x >> 7);
    const int lb = blockIdx.x & 127;
    const int g = lb & 15, member = lb >> 4;
    const int rawwt = member * WPB_ + wave;      // 0..79
    const bool act = rawwt < NT_;
    const int wtile = act ? rawwt : NT_ - 1;
    const int m = lane & 15, oct = lane >> 4;

    {   // one-time: weights -> LDS; zero own-state buffer (h[-1] = 0)
        const short8* wsrc = (layer ? wr1 : wr0) + (size_t)member * (WPB_ * KSR_ * 64);
        for (int i = tid; i < WPB_ * KSR_ * 64; i += 640) wlds[i] = wsrc[i];
        short8 z = {0, 0, 0, 0, 0, 0, 0, 0};
        if (tid < KSR_ * 64) alds[tid] = z;
    }
    short8 wxv;
    if (layer == 0) wxv = wg0[(size_t)wtile * 64 + lane];
    const float* bp = layer ? b1p : b0p;
    const f32x4 b4 = *(const f32x4*)&bp[wtile * 16 + oct * 4];

    unsigned short* r0g = ring0 + (size_t)g * (4 * 5120);
    unsigned short* r1g = ring1 + (size_t)g * (2 * 5120);
    int* c0 = cnt + g * 16;
    int* c1 = cnt + 1024 + g * 16;

    const int jj = wtile * 4 + oct;
    const int fragaddr = (((jj >> 5) * 64 + ((jj >> 3) & 3) * 16 + m) << 3) + (jj & 7);
    unsigned short* houtp = h1rm + ((size_t)(g * 16 + m) * T_) * HP_ + jj;
    const float* xrow = x + ((size_t)(g * 16 + m) * T_) * IN_ + (oct & 1) * 8;
    const short8* xq = wg1 + (size_t)wtile * (KSR_ * 64) + lane;
    const short8* wl = &wlds[wave * (KSR_ * 64) + lane];
    const short8* al = &alds[lane];
    const short8* a0l = &a0lds[lane];
    const short8 z8 = {0, 0, 0, 0, 0, 0, 0, 0};

    __syncthreads();   // wlds/alds ready

    float c = 0.f;

    #pragma unroll 1
    for (int t = 0; t < T_; ++t) {
        f32x4 accC = {0.f, 0.f, 0.f, 0.f}, accD = {0.f, 0.f, 0.f, 0.f};

        if (layer == 0) {
            // x contribution (independent of recurrence)
            const float* xr = xrow + (size_t)t * IN_;
            f32x4 xf0 = *(const f32x4*)xr;
            f32x4 xf1 = *(const f32x4*)(xr + 4);
            S8U xu;
            xu.u[0] = (uint32)f2bf(xf0[0]) | ((uint32)f2bf(xf0[1]) << 16);
            xu.u[1] = (uint32)f2bf(xf0[2]) | ((uint32)f2bf(xf0[3]) << 16);
            xu.u[2] = (uint32)f2bf(xf1[0]) | ((uint32)f2bf(xf1[1]) << 16);
            xu.u[3] = (uint32)f2bf(xf1[2]) | ((uint32)f2bf(xf1[3]) << 16);
            short8 xa = (oct < 2) ? xu.s : z8;
            MF(wxv, xa, accC);

            if (t > 0) {
                // need: all members published h0[t-1]; layer1 consumed h0[t-4]
                if (tid == 0) poll2(c0, c1, MEMB_ * t, MEMB_ * (t - 3));
                __syncthreads();
                const unsigned short* sp = r0g + (size_t)((t - 1) & 3) * 5120
                                         + wave * 512 + lane * 8;
                short8 v = ld16c(sp);
                vm0();
                alds[wave * 64 + lane] = v;
                __syncthreads();
            }
        } else {
            // need: h0[t] published; own members published h1[t-1]
            if (tid == 0) poll2(c0, c1, MEMB_ * (t + 1), MEMB_ * t);
            __syncthreads();
            {
                const unsigned short* sp0 = r0g + (size_t)(t & 3) * 5120
                                          + wave * 512 + lane * 8;
                short8 v0 = ld16c(sp0);
                if (t > 0) {
                    const unsigned short* sp1 = r1g + (size_t)((t - 1) & 1) * 5120
                                              + wave * 512 + lane * 8;
                    short8 v1 = ld16c(sp1);
                    vm0();
                    a0lds[wave * 64 + lane] = v0;
                    alds[wave * 64 + lane] = v1;
                } else {
                    vm0();
                    a0lds[wave * 64 + lane] = v0;
                }
            }
            __syncthreads();
            // Wih1 @ h0[t] (weights stream from L2, constant addresses)
            #pragma unroll
            for (int s = 0; s < KSR_; s += 2) {
                MF(xq[s * 64],       a0l[s * 64],       accC);
                MF(xq[(s + 1) * 64], a0l[(s + 1) * 64], accD);
            }
        }

        // recurrent part: Whh @ h[t-1] from LDS
        f32x4 accA = {0.f, 0.f, 0.f, 0.f}, accB = {0.f, 0.f, 0.f, 0.f};
        #pragma unroll
        for (int s = 0; s < KSR_; s += 2) {
            MF(wl[s * 64],       al[s * 64],       accA);
            MF(wl[(s + 1) * 64], al[(s + 1) * 64], accB);
        }

        float gi = sigm(accA[0] + accB[0] + accC[0] + accD[0] + b4[0]);
        float gf = sigm(accA[1] + accB[1] + accC[1] + accD[1] + b4[1]);
        float gg = tanh_f(accA[2] + accB[2] + accC[2] + accD[2] + b4[2]);
        float go = sigm(accA[3] + accB[3] + accC[3] + accD[3] + b4[3]);
        float cn = gf * c + gi * gg;
        c = cn;
        unsigned short hb = f2bf(go * tanh_f(cn));
        if (act) {
            if (layer == 0) {
                st2c(r0g + (size_t)(t & 3) * 5120 + fragaddr, hb);
            } else {
                st2c(r1g + (size_t)(t & 1) * 5120 + fragaddr, hb);
                houtp[(size_t)t * HP_] = hb;       // row-major for head
            }
        }
        vm0();                                     // stores visible at IF$
        __syncthreads();                           // block done with step t
        if (tid == 0) atomic_inc_cg(layer ? c1 : c0);
    }
}

// ---------------------------------------------------------------------------
// MLP head: W1/W2/W3 staged in LDS (broadcast reads), one thread per position.
// ---------------------------------------------------------------------------
__global__ __launch_bounds__(256) void head_kernel(
    const unsigned short* __restrict__ h1,
    const float* __restrict__ W1, const float* __restrict__ b1,
    const float* __restrict__ W2, const float* __restrict__ b2,
    const float* __restrict__ W3, const float* __restrict__ b3,
    float* __restrict__ out)
{
    __shared__ float w1s[9000];     // 30x300
    __shared__ float w2s[3200];     // 100x32 (padded)
    __shared__ float w3s[100];
    __shared__ float b1s[30];
    __shared__ float b2s[100];
    const int tid = threadIdx.x;
    for (int i = tid; i < 9000; i += 256) w1s[i] = W1[i];
    for (int i = tid; i < 3000; i += 256) w2s[(i / 30) * 32 + (i % 30)] = W2[i];
    if (tid < 100) { w3s[tid] = W3[tid]; b2s[tid] = b2[tid]; }
    if (tid < 30)  b1s[tid] = b1[tid];
    __syncthreads();

    const int pos = blockIdx.x * 256 + tid;
    const unsigned short* hr = h1 + (size_t)pos * HP_;
    float t1[30];
    #pragma unroll
    for (int j = 0; j < 30; ++j) t1[j] = b1s[j];
    for (int kc = 0; kc < H_; kc += 4) {
        uint32 u0 = *(const uint32*)(hr + kc);
        uint32 u1 = *(const uint32*)(hr + kc + 2);
        float h0v = bf2f((unsigned short)(u0 & 0xffffu));
        float h1v = bf2f((unsigned short)(u0 >> 16));
        float h2v = bf2f((unsigned short)(u1 & 0xffffu));
        float h3v = bf2f((unsigned short)(u1 >> 16));
        #pragma unroll
        for (int j = 0; j < 30; ++j) {
            const f32x4 wv = *(const f32x4*)&w1s[j * H_ + kc];
            t1[j] += h0v * wv[0] + h1v * wv[1] + h2v * wv[2] + h3v * wv[3];
        }
    }
    #pragma unroll
    for (int j = 0; j < 30; ++j) t1[j] = tanh_f(t1[j]);
    float oacc = b3[0];
    for (int j2 = 0; j2 < 100; ++j2) {
        float a2 = b2s[j2];
        #pragma unroll
        for (int k = 0; k < 30; ++k) a2 += t1[k] * w2s[j2 * 32 + k];
        oacc += tanh_f(a2) * w3s[j2];
    }
    out[pos] = sigm(oacc);
}

// ---------------------------------------------------------------------------
extern "C" void kernel_launch(void* const* d_in, const int* in_sizes, int n_in,
                              void* d_out, int out_size, void* d_ws, size_t ws_size,
                              hipStream_t stream)
{
    const float* x    = (const float*)d_in[0];
    const float* Wih0 = (const float*)d_in[1];
    const float* Whh0 = (const float*)d_in[2];
    const float* bih0 = (const float*)d_in[3];
    const float* bhh0 = (const float*)d_in[4];
    const float* Wih1 = (const float*)d_in[5];
    const float* Whh1 = (const float*)d_in[6];
    const float* bih1 = (const float*)d_in[7];
    const float* bhh1 = (const float*)d_in[8];
    const float* W1   = (const float*)d_in[9];
    const float* b1   = (const float*)d_in[10];
    const float* W2   = (const float*)d_in[11];
    const float* b2   = (const float*)d_in[12];
    const float* W3   = (const float*)d_in[13];
    const float* b3   = (const float*)d_in[14];

    // buffers sized for 80 tiles so member-7 blocks can bulk-copy safely
    char* ws = (char*)d_ws;
    const size_t OFF_WR0 = 0x000000;   // 819200 B
    const size_t OFF_WG0 = 0x0D0000;   // 81920 B
    const size_t OFF_WR1 = 0x0E8000;   // 819200 B
    const size_t OFF_WG1 = 0x1B0000;   // 819200 B
    const size_t OFF_B0  = 0x280000;   // 4800 B
    const size_t OFF_B1  = 0x282000;   // 4800 B
    const size_t OFF_CNT = 0x284000;   // cnt0 @ +0 (1KB), cnt1 @ +4KB (1KB)
    const size_t OFF_RG0 = 0x290000;   // 16 groups x 4 slots x 10240 B = 655360
    const size_t OFF_RG1 = 0x330000;   // 16 groups x 2 slots x 10240 B = 327680
    const size_t OFF_H1  = 0x400000;   // 41,943,040 B
    const size_t HB      = (size_t)B_ * T_ * HP_ * 2;
    const size_t NEED    = OFF_H1 + HB;          // ~46 MB
    if (ws_size < NEED) return;

    uint32* wr0 = (uint32*)(ws + OFF_WR0);
    uint32* wg0 = (uint32*)(ws + OFF_WG0);
    uint32* wr1 = (uint32*)(ws + OFF_WR1);
    uint32* wg1 = (uint32*)(ws + OFF_WG1);
    float*  b0p = (float*)(ws + OFF_B0);
    float*  b1p = (float*)(ws + OFF_B1);
    int*    cnt = (int*)(ws + OFF_CNT);
    unsigned short* rg0 = (unsigned short*)(ws + OFF_RG0);
    unsigned short* rg1 = (unsigned short*)(ws + OFF_RG1);
    unsigned short* h1b = (unsigned short*)(ws + OFF_H1);

    hipMemsetAsync(ws + OFF_CNT, 0, 8192, stream);   // counters -> epoch 0

    hipLaunchKernelGGL(pack_kernel, dim3(591), dim3(256), 0, stream,
                       Wih0, Whh0, bih0, bhh0, Wih1, Whh1, bih1, bhh1,
                       wr0, wg0, wr1, wg1, b0p, b1p);
    hipLaunchKernelGGL(lstm_dual, dim3(256), dim3(640), 0, stream,
                       x, (const short8*)wr0, (const short8*)wg0,
                       (const short8*)wr1, (const short8*)wg1,
                       b0p, b1p, h1b, rg0, rg1, cnt);
    hipLaunchKernelGGL(head_kernel, dim3(256), dim3(256), 0, stream,
                       h1b, W1, b1, W2, b2, W3, b3, (float*)d_out);
}